// Round 1
// baseline (71.302 us; speedup 1.0000x reference)
//
#include <hip/hip_runtime.h>
#include <cfloat>

// ---------------------------------------------------------------------------
// VQ-VAE vector quantizer forward (MI355X / gfx950)
//   x        [32][64][64][64] f32   (B, D, H, W)
//   codebook [1024][64] f32
// out: x_q transposed back to [B,D,H,W] (8388608 f32)  +  loss scalar (1 f32)
//
// argmin_k ||x - c_k||^2  ==  argmax_k (x . c_k - ||c_k||^2/2)
// loss = 1.25 * mean(||x - c_idx||^2) ; SSE(pos) = ||x||^2 - 2 * s_best
// ---------------------------------------------------------------------------

#define DD   64
#define HHWW 4096          // H*W
#define KC   1024
#define NROWS 2048         // B*H rows of 64 positions
#define NBLK  512          // NROWS / 4 waves
#define NPOSD 8388608.0f   // N * D

typedef __bf16  bf16x8 __attribute__((ext_vector_type(8)));
typedef unsigned short u16x8 __attribute__((ext_vector_type(8)));
typedef float   f32x4  __attribute__((ext_vector_type(4)));

__device__ __forceinline__ unsigned short bf16_bits(float f) {
  unsigned u = __float_as_uint(f);
  return (unsigned short)((u + 0x7FFFu + ((u >> 16) & 1u)) >> 16);  // RNE
}

// --- precompute: fragment-ordered bf16 codebook, -||c||^2/2, codebook^T -----
__global__ __launch_bounds__(256) void vq_pre(
    const float* __restrict__ cb,          // [1024][64]
    unsigned short* __restrict__ cb_frag,  // [tile=64][kk=2][lane=64][e=8]
    float* __restrict__ hneg,              // [1024]
    float* __restrict__ cbT)               // [64][1024]
{
  int k = blockIdx.x * 256 + threadIdx.x;
  if (k >= KC) return;
  float c[DD];
  float sum = 0.f;
#pragma unroll
  for (int d = 0; d < DD; ++d) { c[d] = cb[k * DD + d]; sum += c[d] * c[d]; }
  hneg[k] = -0.5f * sum;
#pragma unroll
  for (int d = 0; d < DD; ++d) cbT[d * KC + k] = c[d];
  int t = k >> 4, l15 = k & 15;
#pragma unroll
  for (int kk = 0; kk < 2; ++kk)
#pragma unroll
    for (int g = 0; g < 4; ++g)
#pragma unroll
      for (int e = 0; e < 8; ++e)
        cb_frag[(((t * 2 + kk) * 64) + (g * 16 + l15)) * 8 + e] =
            bf16_bits(c[kk * 32 + g * 8 + e]);
}

// --- main: fused distance-GEMM + argmin + loss partial + output write ------
__global__ __launch_bounds__(256) void vq_main(
    const float* __restrict__ x,
    const unsigned short* __restrict__ cb_frag,
    const float* __restrict__ hneg,
    const float* __restrict__ cbT,
    float* __restrict__ out,
    float* __restrict__ partials)
{
  __shared__ float xsq_lds[256];
  __shared__ int   idx_lds[256];
  __shared__ float sse_lds[256];

  const int tid  = threadIdx.x;
  const int wv   = tid >> 6;
  const int lane = tid & 63;
  const int l15  = lane & 15;
  const int g    = lane >> 4;

  const int row = blockIdx.x * 4 + wv;   // global (b,h) row, 0..2047
  const int b   = row >> 6;
  const int h   = row & 63;
  const float* xb = x + (size_t)b * DD * HHWW + h * 64;  // xb[d*4096 + w]

  // ---- load A fragments (x, bf16) and per-position ||x||^2 ----
  // A layout convention (consistent with B): row i = lane&15,
  // k = kk*32 + (lane>>4)*8 + e  -- any HW k-permutation cancels since the
  // identical convention is used for both operands.
  bf16x8 afrag[4][2];
  float  xsq[4];
#pragma unroll
  for (int pt = 0; pt < 4; ++pt) {
    const int w = pt * 16 + l15;
    float s = 0.f;
#pragma unroll
    for (int kk = 0; kk < 2; ++kk) {
      const int dbase = kk * 32 + g * 8;
      u16x8 f;
#pragma unroll
      for (int e = 0; e < 8; ++e) {
        float v = xb[(size_t)(dbase + e) * HHWW + w];
        s += v * v;
        f[e] = bf16_bits(v);
      }
      afrag[pt][kk] = __builtin_bit_cast(bf16x8, f);
    }
    s += __shfl_xor(s, 16, 64);
    s += __shfl_xor(s, 32, 64);
    xsq[pt] = s;                       // full sum over 64 dims
  }
  if (g == 0) {
#pragma unroll
    for (int pt = 0; pt < 4; ++pt) xsq_lds[wv * 64 + pt * 16 + l15] = xsq[pt];
  }

  // ---- scan 64 code tiles ----
  float best_s[4][4];
  int   best_c[4][4];
#pragma unroll
  for (int pt = 0; pt < 4; ++pt)
#pragma unroll
    for (int r = 0; r < 4; ++r) { best_s[pt][r] = -FLT_MAX; best_c[pt][r] = 0; }

  for (int tc = 0; tc < 64; ++tc) {
    const float mh = hneg[tc * 16 + l15];          // folded into C-init
    const bf16x8* bptr = (const bf16x8*)(cb_frag + (size_t)tc * 2 * 64 * 8);
    const bf16x8 b0 = bptr[lane];       // kk=0, coalesced 1KB/wave
    const bf16x8 b1 = bptr[64 + lane];  // kk=1
    f32x4 acc[4];
#pragma unroll
    for (int pt = 0; pt < 4; ++pt) acc[pt] = (f32x4){mh, mh, mh, mh};
#pragma unroll
    for (int pt = 0; pt < 4; ++pt)
      acc[pt] = __builtin_amdgcn_mfma_f32_16x16x32_bf16(afrag[pt][0], b0, acc[pt], 0, 0, 0);
#pragma unroll
    for (int pt = 0; pt < 4; ++pt)
      acc[pt] = __builtin_amdgcn_mfma_f32_16x16x32_bf16(afrag[pt][1], b1, acc[pt], 0, 0, 0);
    const int code = tc * 16 + l15;
#pragma unroll
    for (int pt = 0; pt < 4; ++pt)
#pragma unroll
      for (int r = 0; r < 4; ++r) {
        float v = acc[pt][r];          // C/D: col=lane&15(code), row=g*4+r(pos)
        if (v > best_s[pt][r]) { best_s[pt][r] = v; best_c[pt][r] = code; }
      }
  }

  // ---- cross-lane argmax over the 16 code classes (lane&15) ----
#pragma unroll
  for (int pt = 0; pt < 4; ++pt)
#pragma unroll
    for (int r = 0; r < 4; ++r) {
      float s = best_s[pt][r];
      int   c = best_c[pt][r];
#pragma unroll
      for (int m = 1; m < 16; m <<= 1) {
        float so = __shfl_xor(s, m, 64);
        int   co = __shfl_xor(c, m, 64);
        if (so > s || (so == s && co < c)) { s = so; c = co; }
      }
      if (l15 == 0) {
        int p = pt * 16 + g * 4 + r;
        idx_lds[wv * 64 + p] = c;
        sse_lds[wv * 64 + p] = xsq_lds[wv * 64 + p] - 2.0f * s;
      }
    }

  __syncthreads();

  // ---- block loss partial ----
  if (wv == 0) {
    float t = sse_lds[lane] + sse_lds[64 + lane] + sse_lds[128 + lane] +
              sse_lds[192 + lane];
#pragma unroll
    for (int m = 1; m < 64; m <<= 1) t += __shfl_xor(t, m, 64);
    if (lane == 0) partials[blockIdx.x] = t;
  }

  // ---- write quantized output (transposed back, coalesced per d-row) ----
  const int myidx = idx_lds[tid];      // position w = lane of row (b,h)=wv's row
  float* ob = out + (size_t)b * DD * HHWW + h * 64;
#pragma unroll 8
  for (int d = 0; d < DD; ++d) {
    ob[(size_t)d * HHWW + lane] = cbT[d * KC + myidx];
  }
}

// --- final loss reduce ------------------------------------------------------
__global__ __launch_bounds__(256) void vq_loss(
    const float* __restrict__ partials, float* __restrict__ loss_out)
{
  __shared__ float sred[4];
  int tid = threadIdx.x;
  float s = 0.f;
  for (int i = tid; i < NBLK; i += 256) s += partials[i];
#pragma unroll
  for (int m = 1; m < 64; m <<= 1) s += __shfl_xor(s, m, 64);
  if ((tid & 63) == 0) sred[tid >> 6] = s;
  __syncthreads();
  if (tid == 0)
    loss_out[0] = (sred[0] + sred[1] + sred[2] + sred[3]) * (1.25f / NPOSD);
}

extern "C" void kernel_launch(void* const* d_in, const int* in_sizes, int n_in,
                              void* d_out, int out_size, void* d_ws, size_t ws_size,
                              hipStream_t stream) {
  const float* x  = (const float*)d_in[0];
  const float* cb = (const float*)d_in[1];
  float* out      = (float*)d_out;
  float* loss_out = out + 8388608;

  char* ws = (char*)d_ws;
  unsigned short* cb_frag = (unsigned short*)(ws);      // 131072 B
  float* hneg     = (float*)(ws + 131072);              //   4096 B
  float* cbT      = (float*)(ws + 135168);              // 262144 B
  float* partials = (float*)(ws + 397312);              //   2048 B

  vq_pre <<<4,    256, 0, stream>>>(cb, cb_frag, hneg, cbT);
  vq_main<<<NBLK, 256, 0, stream>>>(x, cb_frag, hneg, cbT, out, partials);
  vq_loss<<<1,    256, 0, stream>>>(partials, loss_out);
}